// Round 18
// baseline (751.466 us; speedup 1.0000x reference)
//
#include <hip/hip_runtime.h>
#include <hip/hip_bf16.h>
#include <hip/hip_cooperative_groups.h>
#include <math.h>

namespace cg = cooperative_groups;

constexpr int IN_DIM = 128;
constexpr int HID    = 64;
constexpr int OUTD   = 16;
constexpr int BSH    = 9;       // bucket shift: bucket = dst >> 9 (512 nodes/bucket)
constexpr float QS   = 4.0f;    // fixed quant range: |h*dinv| < 4 analytically

typedef __attribute__((ext_vector_type(8))) short short8v;
typedef __attribute__((ext_vector_type(4))) float f32x4;

// NOTE: harness delivers integer inputs as int32.
// NOTE: no global atomics — LDS-privatized partition (R9/R10).
// NOTE: int8 h2q + sdot4 byte-select agg; zero row at index n for invalid slots.
// NOTE: R18 = cooperative mega-kernel: 6 launches -> 1, edges held in REGISTERS
//       across hist->scatter, gemm on blocks 256+ during all partition phases.
//       Fallback to the proven 6-launch path if cooperative launch errors.

#if __has_builtin(__builtin_amdgcn_sdot4)
#define SDOT4(a, b, c) __builtin_amdgcn_sdot4((int)(a), (int)(b), (c), false)
#else
__device__ __forceinline__ int SDOT4(unsigned a, unsigned b, int c) {
    return c + (int)(signed char)(a) * (int)(signed char)(b)
             + (int)(signed char)(a >> 8)  * (int)(signed char)(b >> 8)
             + (int)(signed char)(a >> 16) * (int)(signed char)(b >> 16)
             + (int)(signed char)(a >> 24) * (int)(signed char)(b >> 24);
}
#endif

// ---------------------------------------------------------------- block-wide exclusive scan of 256 ints
__device__ __forceinline__ int blockScan256(int v, volatile int* wsum) {
    int tid = threadIdx.x, lane = tid & 63, w = tid >> 6;
    int x = v;
#pragma unroll
    for (int off = 1; off < 64; off <<= 1) {
        int t = __shfl_up(x, off, 64);
        if (lane >= off) x += t;
    }
    if (lane == 63) wsum[w] = x;
    __syncthreads();
    int add = 0;
#pragma unroll
    for (int ww = 0; ww < 4; ++ww) if (ww < w) add += wsum[ww];
    int ex = x + add - v;
    __syncthreads();
    return ex;
}

// ---------------------------------------------------------------- MFMA gemm slice: h2[t0..t1) = x @ W1 (bf16, unscaled)
__device__ __forceinline__ void gemm_slice(const float* __restrict__ x,
                                           const float* __restrict__ W1,
                                           __hip_bfloat16* __restrict__ h2,
                                           int n, int t0, int t1,
                                           int gwid, int gnw) {
    int lane = threadIdx.x & 63;
    int m16  = lane & 15;
    int kg   = lane >> 4;
    if (t0 >= t1) return;

    union { __hip_bfloat16 b; unsigned short u; } cv;

    short8v bfr[4][4];
#pragma unroll
    for (int s = 0; s < 4; ++s)
#pragma unroll
        for (int t = 0; t < 4; ++t) {
            const float* wp = W1 + (size_t)(32 * s + 8 * kg) * HID + 16 * t + m16;
#pragma unroll
            for (int e = 0; e < 8; ++e) {
                cv.b = __float2bfloat16(wp[(size_t)e * HID]);
                bfr[s][t][e] = (short)cv.u;
            }
        }

    for (int tile = t0 + gwid; tile < t1; tile += gnw) {
        int base = tile * 16;
        int row = base + m16; if (row > n - 1) row = n - 1;
        const float* xrow = x + (size_t)row * IN_DIM + 8 * kg;

        short8v a[4];
#pragma unroll
        for (int s = 0; s < 4; ++s) {
            float4 lo = *(const float4*)(xrow + 32 * s);
            float4 hi = *(const float4*)(xrow + 32 * s + 4);
            cv.b = __float2bfloat16(lo.x); a[s][0] = (short)cv.u;
            cv.b = __float2bfloat16(lo.y); a[s][1] = (short)cv.u;
            cv.b = __float2bfloat16(lo.z); a[s][2] = (short)cv.u;
            cv.b = __float2bfloat16(lo.w); a[s][3] = (short)cv.u;
            cv.b = __float2bfloat16(hi.x); a[s][4] = (short)cv.u;
            cv.b = __float2bfloat16(hi.y); a[s][5] = (short)cv.u;
            cv.b = __float2bfloat16(hi.z); a[s][6] = (short)cv.u;
            cv.b = __float2bfloat16(hi.w); a[s][7] = (short)cv.u;
        }

        f32x4 acc[4];
#pragma unroll
        for (int t = 0; t < 4; ++t) acc[t] = (f32x4){0.f, 0.f, 0.f, 0.f};
#pragma unroll
        for (int s = 0; s < 4; ++s) {
#pragma unroll
            for (int t = 0; t < 4; ++t)
                acc[t] = __builtin_amdgcn_mfma_f32_16x16x32_bf16(a[s], bfr[s][t], acc[t], 0, 0, 0);
        }

#pragma unroll
        for (int r = 0; r < 4; ++r) {
            int node = base + 4 * kg + r;
            if (node < n) {
                __hip_bfloat16* hp = h2 + (size_t)node * HID + m16;
                hp[0]  = __float2bfloat16(acc[0][r]);
                hp[16] = __float2bfloat16(acc[1][r]);
                hp[32] = __float2bfloat16(acc[2][r]);
                hp[48] = __float2bfloat16(acc[3][r]);
            }
        }
    }
}

// ---------------------------------------------------------------- quantize one 16-node tile (fixed scale, zero-pad rows >= n)
__device__ __forceinline__ void quant_tile(const __hip_bfloat16* __restrict__ h2,
                                           const float* __restrict__ dinv,
                                           signed char* __restrict__ h2q,
                                           int n, int wv, int lane) {
    int base = wv * 16;
    int row  = lane >> 2;
    int part = lane & 3;
    int node = base + row;

    if (node >= n) {
        if (node < n + 16)
            ((uint4*)(h2q + (size_t)node * HID))[part] = make_uint4(0u, 0u, 0u, 0u);
        return;
    }

    const uint4* hrow = (const uint4*)(h2 + (size_t)node * HID);
    uint4 hA = hrow[2 * part];
    uint4 hB = hrow[2 * part + 1];
    float dv = dinv[node] * (127.f / QS);

#define UB(u) __uint_as_float((u) << 16)
#define UT(u) __uint_as_float((u) & 0xffff0000u)
#define QC(u) __float2int_rn(fmaxf(fminf((u), 127.f), -127.f))
    int q0 = QC(UB(hA.x) * dv), q1 = QC(UT(hA.x) * dv);
    int q2 = QC(UB(hA.y) * dv), q3 = QC(UT(hA.y) * dv);
    int q4 = QC(UB(hA.z) * dv), q5 = QC(UT(hA.z) * dv);
    int q6 = QC(UB(hA.w) * dv), q7 = QC(UT(hA.w) * dv);
    int q8 = QC(UB(hB.x) * dv), q9 = QC(UT(hB.x) * dv);
    int q10 = QC(UB(hB.y) * dv), q11 = QC(UT(hB.y) * dv);
    int q12 = QC(UB(hB.z) * dv), q13 = QC(UT(hB.z) * dv);
    int q14 = QC(UB(hB.w) * dv), q15 = QC(UT(hB.w) * dv);
#undef UB
#undef UT
#undef QC
    unsigned w0 = (q0 & 255) | ((q1 & 255) << 8) | ((q2 & 255) << 16) | ((unsigned)(q3 & 255) << 24);
    unsigned w1 = (q4 & 255) | ((q5 & 255) << 8) | ((q6 & 255) << 16) | ((unsigned)(q7 & 255) << 24);
    unsigned w2 = (q8 & 255) | ((q9 & 255) << 8) | ((q10 & 255) << 16) | ((unsigned)(q11 & 255) << 24);
    unsigned w3 = (q12 & 255) | ((q13 & 255) << 8) | ((q14 & 255) << 16) | ((unsigned)(q15 & 255) << 24);
    ((uint4*)(h2q + (size_t)node * HID))[part] = make_uint4(w0, w1, w2, w3);
}

// ---------------------------------------------------------------- agg one batch of 8 nodes (one wave)
__device__ __forceinline__ void agg_batch(const signed char* __restrict__ h2q,
                                          const float* __restrict__ dinv,
                                          const int* __restrict__ offs,
                                          const int* __restrict__ ebuf,
                                          const int* __restrict__ perm,
                                          const float* __restrict__ b1,
                                          const float* __restrict__ w2s,
                                          const float* __restrict__ b2,
                                          float* __restrict__ out,
                                          int n, int bat, int lane) {
    const unsigned B0 = 0x00000001u, B1 = 0x00000100u, B2 = 0x00010000u, B3 = 0x01000000u;
    int sub = lane >> 3;
    int f   = lane & 7;
    int idx = bat * 8 + sub;
    bool nv = idx < n;
    int node = nv ? perm[idx] : 0;

    float dn = dinv[node];
    float4 b1A = ((const float4*)b1)[2 * f];
    float4 b1B = ((const float4*)b1)[2 * f + 1];
    float b2l0 = b2[2 * f], b2l1 = b2[2 * f + 1];

    const uint2* q = (const uint2*)h2q;

    uint2 svv = q[(size_t)node * 8 + f];
    int ai0 = SDOT4(svv.x, B0, 0), ai1 = SDOT4(svv.x, B1, 0);
    int ai2 = SDOT4(svv.x, B2, 0), ai3 = SDOT4(svv.x, B3, 0);
    int ai4 = SDOT4(svv.y, B0, 0), ai5 = SDOT4(svv.y, B1, 0);
    int ai6 = SDOT4(svv.y, B2, 0), ai7 = SDOT4(svv.y, B3, 0);

    int start = 0, end = 0;
    if (nv) { start = offs[idx == 0 ? node : node]; start = offs[node]; end = offs[node + 1]; }

    int cur = start;
    int p0 = (cur     < end) ? ebuf[cur]     : n;
    int p1 = (cur + 1 < end) ? ebuf[cur + 1] : n;
    int p2 = (cur + 2 < end) ? ebuf[cur + 2] : n;
    int p3 = (cur + 3 < end) ? ebuf[cur + 3] : n;

    while (__any(cur < end)) {
        int s0 = p0, s1 = p1, s2 = p2, s3 = p3;
        int ncur = cur + 4;

        uint2 g0 = q[(size_t)s0 * 8 + f];
        uint2 g1 = q[(size_t)s1 * 8 + f];
        uint2 g2 = q[(size_t)s2 * 8 + f];
        uint2 g3 = q[(size_t)s3 * 8 + f];

        p0 = (ncur     < end) ? ebuf[ncur]     : n;
        p1 = (ncur + 1 < end) ? ebuf[ncur + 1] : n;
        p2 = (ncur + 2 < end) ? ebuf[ncur + 2] : n;
        p3 = (ncur + 3 < end) ? ebuf[ncur + 3] : n;

#define ACCQ(g) \
        ai0 = SDOT4(g.x, B0, ai0); ai1 = SDOT4(g.x, B1, ai1); \
        ai2 = SDOT4(g.x, B2, ai2); ai3 = SDOT4(g.x, B3, ai3); \
        ai4 = SDOT4(g.y, B0, ai4); ai5 = SDOT4(g.y, B1, ai5); \
        ai6 = SDOT4(g.y, B2, ai6); ai7 = SDOT4(g.y, B3, ai7);
        ACCQ(g0) ACCQ(g1) ACCQ(g2) ACCQ(g3)
#undef ACCQ
        cur = ncur;
    }

    float sc = dn * (QS / 127.f);
    float r0 = fmaxf(fmaf((float)ai0, sc, b1A.x), 0.f);
    float r1 = fmaxf(fmaf((float)ai1, sc, b1A.y), 0.f);
    float r2 = fmaxf(fmaf((float)ai2, sc, b1A.z), 0.f);
    float r3 = fmaxf(fmaf((float)ai3, sc, b1A.w), 0.f);
    float r4 = fmaxf(fmaf((float)ai4, sc, b1B.x), 0.f);
    float r5 = fmaxf(fmaf((float)ai5, sc, b1B.y), 0.f);
    float r6 = fmaxf(fmaf((float)ai6, sc, b1B.z), 0.f);
    float r7 = fmaxf(fmaf((float)ai7, sc, b1B.w), 0.f);

    float q0 = b2l0, q1 = b2l1;
    int subbase = lane & 56;
#pragma unroll
    for (int j2 = 0; j2 < 8; ++j2) {
        int srcl = subbase | j2;
        float rv0 = __shfl(r0, srcl, 64);
        float rv1 = __shfl(r1, srcl, 64);
        float rv2 = __shfl(r2, srcl, 64);
        float rv3 = __shfl(r3, srcl, 64);
        float rv4 = __shfl(r4, srcl, 64);
        float rv5 = __shfl(r5, srcl, 64);
        float rv6 = __shfl(r6, srcl, 64);
        float rv7 = __shfl(r7, srcl, 64);
        const float2* wrow = (const float2*)(w2s + 8 * j2 * OUTD + 2 * f);
        float2 w0 = wrow[0];  q0 = fmaf(rv0, w0.x, q0); q1 = fmaf(rv0, w0.y, q1);
        float2 w1 = wrow[8];  q0 = fmaf(rv1, w1.x, q0); q1 = fmaf(rv1, w1.y, q1);
        float2 w2 = wrow[16]; q0 = fmaf(rv2, w2.x, q0); q1 = fmaf(rv2, w2.y, q1);
        float2 w3 = wrow[24]; q0 = fmaf(rv3, w3.x, q0); q1 = fmaf(rv3, w3.y, q1);
        float2 w4 = wrow[32]; q0 = fmaf(rv4, w4.x, q0); q1 = fmaf(rv4, w4.y, q1);
        float2 w5 = wrow[40]; q0 = fmaf(rv5, w5.x, q0); q1 = fmaf(rv5, w5.y, q1);
        float2 w6 = wrow[48]; q0 = fmaf(rv6, w6.x, q0); q1 = fmaf(rv6, w6.y, q1);
        float2 w7 = wrow[56]; q0 = fmaf(rv7, w7.x, q0); q1 = fmaf(rv7, w7.y, q1);
    }

    float m = fmaxf(q0, q1);
    m = fmaxf(m, __shfl_xor(m, 1, 64));
    m = fmaxf(m, __shfl_xor(m, 2, 64));
    m = fmaxf(m, __shfl_xor(m, 4, 64));
    float ssum = __expf(q0 - m) + __expf(q1 - m);
    ssum += __shfl_xor(ssum, 1, 64);
    ssum += __shfl_xor(ssum, 2, 64);
    ssum += __shfl_xor(ssum, 4, 64);
    float lg = __logf(ssum);

    if (nv) {
        float2 o = make_float2(q0 - m - lg, q1 - m - lg);
        *(float2*)(out + (size_t)node * OUTD + 2 * f) = o;
    }
}

// ================================================================ MEGA (cooperative)
__global__ __launch_bounds__(256, 4) void k_mega(const int* ei, int E, int CH, int nbuk, int n,
                                                 const float* x, const float* W1,
                                                 __hip_bfloat16* h2, signed char* h2q, float* dinv,
                                                 int* offs, int* ebuf, unsigned* sdbuf,
                                                 int* gh, int* total, int* perm,
                                                 const float* b1, const float* W2, const float* b2,
                                                 float* out, int G, int c1, int c2, int c3, int ntile) {
    cg::grid_group grid = cg::this_grid();
    int b = blockIdx.x, t = threadIdx.x;
    int gnw = (G - 256) * 4;
    int gwid = (b >= 256) ? (((b - 256) * 256 + t) >> 6) : 0;

    __shared__ int sh_hist[256];
    __shared__ int sh_wsum[4];
    __shared__ int sh_cursor[256];
    __shared__ int sh_degl[512];
    __shared__ int sh_offl[512];
    __shared__ int sh_lohi[2];
    __shared__ int sh_dh[128];
    __shared__ float sh_w2s[HID * OUTD];

    int se[16], de[16];
    int e0 = b * CH, e1 = min(E, e0 + CH);

    // ---- P0: hist + edge load to regs (b<256) || gemm A ----
    if (b < 256) {
        sh_hist[t] = 0;
        __syncthreads();
#pragma unroll
        for (int k = 0; k < 16; ++k) {
            int e = e0 + k * 256 + t;
            bool v = e < e1;
            se[k] = v ? ei[e] : 0;
            de[k] = v ? ei[E + e] : -1;
            if (v) atomicAdd(&sh_hist[de[k] >> BSH], 1);
        }
        __syncthreads();
        gh[t * 256 + b] = sh_hist[t];
    } else {
        gemm_slice(x, W1, h2, n, 0, c1, gwid, gnw);
    }
    grid.sync();

    // ---- P1: colscan (b<nbuk) || gemm B ----
    if (b < nbuk) {
        int v = gh[b * 256 + t];
        int ex = blockScan256(v, sh_wsum);
        gh[b * 256 + t] = ex;
        if (t == 255) total[b] = ex + v;
    } else if (b >= 256) {
        gemm_slice(x, W1, h2, n, c1, c2, gwid, gnw);
    }
    grid.sync();

    // ---- P2: scatter from regs (b<256) || gemm C ----
    if (b < 256) {
        int tv = (t < nbuk) ? total[t] : 0;
        int bbase = blockScan256(tv, sh_wsum);
        sh_cursor[t] = gh[t * 256 + b] + bbase;
        __syncthreads();
#pragma unroll
        for (int k = 0; k < 16; ++k) {
            if (de[k] >= 0) {
                int pos = atomicAdd(&sh_cursor[de[k] >> BSH], 1);
                sdbuf[pos] = ((unsigned)se[k] << BSH) | ((unsigned)de[k] & 511u);
            }
        }
    } else {
        gemm_slice(x, W1, h2, n, c2, c3, gwid, gnw);
    }
    grid.sync();

    // ---- P3: csr (b<nbuk) || gemm D ----
    if (b < nbuk) {
        sh_degl[t] = 0; sh_degl[t + 256] = 0;
        if (t < 128) sh_dh[t] = 0;

        int tv = (t < nbuk) ? total[t] : 0;
        int ex = blockScan256(tv, sh_wsum);
        if (t == b) { sh_lohi[0] = ex; sh_lohi[1] = ex + tv; }
        __syncthreads();
        int lo = sh_lohi[0], hi = sh_lohi[1];

        for (int i = lo + t; i < hi; i += 256)
            atomicAdd(&sh_degl[(int)(sdbuf[i] & 511u)], 1);
        __syncthreads();

        int d0 = sh_degl[2 * t], d1 = sh_degl[2 * t + 1];
        int pex = blockScan256(d0 + d1, sh_wsum);
        sh_offl[2 * t]     = pex;
        sh_offl[2 * t + 1] = pex + d0;
        __syncthreads();

        int base = b << BSH;
        int bsize = min(512, n - base);
#pragma unroll
        for (int k = 0; k < 512; k += 256) {
            int i = t + k;
            int node = base + i;
            if (node <= n) offs[node] = lo + sh_offl[i];
            if (i < bsize) {
                dinv[node] = rsqrtf((float)(sh_degl[i] + 1));
                atomicAdd(&sh_dh[127 - min(sh_degl[i], 127)], 1);
            }
        }
        __syncthreads();

        int hv = (t < 128) ? sh_dh[t] : 0;
        int hex = blockScan256(hv, sh_wsum);
        if (t < 128) sh_dh[t] = hex;
        __syncthreads();

#pragma unroll
        for (int k = 0; k < 512; k += 256) {
            int i = t + k;
            if (i < bsize) {
                int r = atomicAdd(&sh_dh[127 - min(sh_degl[i], 127)], 1);
                perm[base + r] = base + i;
            }
        }

        for (int i = lo + t; i < hi; i += 256) {
            unsigned v = sdbuf[i];
            int pos = lo + atomicAdd(&sh_offl[(int)(v & 511u)], 1);
            ebuf[pos] = (int)(v >> BSH);
        }
    } else if (b >= 256) {
        gemm_slice(x, W1, h2, n, c3, ntile, gwid, gnw);
    }
    grid.sync();

    // ---- P4: quant (all blocks, grid-stride waves; tile==ntile is zero-pad) ----
    {
        int lane = t & 63;
        int wv0 = (b * 256 + t) >> 6;
        int nw = G * 4;
        for (int wv = wv0; wv <= ntile; wv += nw)
            quant_tile(h2, dinv, h2q, n, wv, lane);
    }
    grid.sync();

    // ---- P5: agg (all blocks, grid-stride batches) ----
    for (int i = t; i < HID * OUTD; i += 256) sh_w2s[i] = W2[i];
    __syncthreads();
    {
        int lane = t & 63;
        int wv0 = (b * 256 + t) >> 6;
        int nw = G * 4;
        int nbatch = (n + 7) / 8;
        for (int bat = wv0; bat < nbatch; bat += nw)
            agg_batch(h2q, dinv, offs, ebuf, perm, b1, sh_w2s, b2, out, n, bat, lane);
    }
}

// ================================================================ FALLBACK kernels (R17 path)
__global__ __launch_bounds__(256) void k_hist(const int* __restrict__ dst,
                                              int* __restrict__ gh, int E, int CH,
                                              const float* __restrict__ x,
                                              const float* __restrict__ W1,
                                              __hip_bfloat16* __restrict__ h2,
                                              int n, int t0, int t1, int gblk) {
    if ((int)blockIdx.x >= 256) {
        int gwid = ((blockIdx.x - 256) * 256 + threadIdx.x) >> 6;
        gemm_slice(x, W1, h2, n, t0, t1, gwid, gblk * 4);
        return;
    }
    __shared__ int hist[256];
    int t = threadIdx.x, b = blockIdx.x;
    hist[t] = 0;
    __syncthreads();
    int e0 = b * CH, e1 = min(E, e0 + CH);
    for (int e = e0 + t; e < e1; e += 256)
        atomicAdd(&hist[dst[e] >> BSH], 1);
    __syncthreads();
    gh[t * 256 + b] = hist[t];
}

__global__ __launch_bounds__(256) void k_colscan(int* __restrict__ gh,
                                                 int* __restrict__ total, int nbuk,
                                                 const float* __restrict__ x,
                                                 const float* __restrict__ W1,
                                                 __hip_bfloat16* __restrict__ h2,
                                                 int n, int t0, int t1, int gblk) {
    if ((int)blockIdx.x >= nbuk) {
        int gwid = ((blockIdx.x - nbuk) * 256 + threadIdx.x) >> 6;
        gemm_slice(x, W1, h2, n, t0, t1, gwid, gblk * 4);
        return;
    }
    __shared__ int wsum[4];
    int bu = blockIdx.x, t = threadIdx.x;
    int v = gh[bu * 256 + t];
    int ex = blockScan256(v, wsum);
    gh[bu * 256 + t] = ex;
    if (t == 255) total[bu] = ex + v;
}

__global__ __launch_bounds__(256) void k_scat(const int* __restrict__ ei,
                                              const int* __restrict__ gh,
                                              const int* __restrict__ total,
                                              unsigned* __restrict__ sdbuf,
                                              int E, int CH, int nbuk,
                                              const float* __restrict__ x,
                                              const float* __restrict__ W1,
                                              __hip_bfloat16* __restrict__ h2,
                                              int n, int t0, int t1, int gblk) {
    if ((int)blockIdx.x >= 256) {
        int gwid = ((blockIdx.x - 256) * 256 + threadIdx.x) >> 6;
        gemm_slice(x, W1, h2, n, t0, t1, gwid, gblk * 4);
        return;
    }
    __shared__ int cursor[256];
    __shared__ int wsum[4];
    int t = threadIdx.x, b = blockIdx.x;
    int tv = (t < nbuk) ? total[t] : 0;
    int bbase = blockScan256(tv, wsum);
    cursor[t] = gh[t * 256 + b] + bbase;
    __syncthreads();
    int e0 = b * CH, e1 = min(E, e0 + CH);
    for (int e = e0 + t; e < e1; e += 256) {
        int s = ei[e];
        int d = ei[E + e];
        int pos = atomicAdd(&cursor[d >> BSH], 1);
        sdbuf[pos] = ((unsigned)s << BSH) | ((unsigned)d & 511u);
    }
}

__global__ __launch_bounds__(256) void k_csr(const unsigned* __restrict__ sdbuf,
                                             const int* __restrict__ total,
                                             int* __restrict__ offs,
                                             float* __restrict__ dinv,
                                             int* __restrict__ ebuf,
                                             int* __restrict__ perm,
                                             int n, int nbuk,
                                             const float* __restrict__ x,
                                             const float* __restrict__ W1,
                                             __hip_bfloat16* __restrict__ h2,
                                             int t0, int t1, int gblk) {
    if ((int)blockIdx.x >= nbuk) {
        int gwid = ((blockIdx.x - nbuk) * 256 + threadIdx.x) >> 6;
        gemm_slice(x, W1, h2, n, t0, t1, gwid, gblk * 4);
        return;
    }
    __shared__ int degl[512];
    __shared__ int offl[512];
    __shared__ int wsum[4];
    __shared__ int lohi[2];
    __shared__ int dh[128];
    int bu = blockIdx.x, t = threadIdx.x;
    degl[t] = 0; degl[t + 256] = 0;
    if (t < 128) dh[t] = 0;

    int tv = (t < nbuk) ? total[t] : 0;
    int ex = blockScan256(tv, wsum);
    if (t == bu) { lohi[0] = ex; lohi[1] = ex + tv; }
    __syncthreads();
    int lo = lohi[0], hi = lohi[1];

    for (int i = lo + t; i < hi; i += 256)
        atomicAdd(&degl[(int)(sdbuf[i] & 511u)], 1);
    __syncthreads();

    int d0 = degl[2 * t], d1 = degl[2 * t + 1];
    int pex = blockScan256(d0 + d1, wsum);
    offl[2 * t]     = pex;
    offl[2 * t + 1] = pex + d0;
    __syncthreads();

    int base = bu << BSH;
    int bsize = min(512, n - base);
#pragma unroll
    for (int k = 0; k < 512; k += 256) {
        int i = t + k;
        int node = base + i;
        if (node <= n) offs[node] = lo + offl[i];
        if (i < bsize) {
            dinv[node] = rsqrtf((float)(degl[i] + 1));
            atomicAdd(&dh[127 - min(degl[i], 127)], 1);
        }
    }
    __syncthreads();

    int hv = (t < 128) ? dh[t] : 0;
    int hex = blockScan256(hv, wsum);
    if (t < 128) dh[t] = hex;
    __syncthreads();

#pragma unroll
    for (int k = 0; k < 512; k += 256) {
        int i = t + k;
        if (i < bsize) {
            int r = atomicAdd(&dh[127 - min(degl[i], 127)], 1);
            perm[base + r] = base + i;
        }
    }

    for (int i = lo + t; i < hi; i += 256) {
        unsigned v = sdbuf[i];
        int pos = lo + atomicAdd(&offl[(int)(v & 511u)], 1);
        ebuf[pos] = (int)(v >> BSH);
    }
}

__global__ __launch_bounds__(256) void k_quant(const __hip_bfloat16* __restrict__ h2,
                                               const float* __restrict__ dinv,
                                               signed char* __restrict__ h2q, int n) {
    int lane = threadIdx.x & 63;
    int wv   = (blockIdx.x * 256 + threadIdx.x) >> 6;
    int ntile = (n + 15) >> 4;
    if (wv > ntile) return;
    quant_tile(h2, dinv, h2q, n, wv, lane);
}

__global__ __launch_bounds__(256) void k_agg(const signed char* __restrict__ h2q,
                                             const float* __restrict__ dinv,
                                             const int* __restrict__ offs,
                                             const int* __restrict__ ebuf,
                                             const int* __restrict__ perm,
                                             const float* __restrict__ b1,
                                             const float* __restrict__ W2,
                                             const float* __restrict__ b2,
                                             float* __restrict__ out, int n) {
    __shared__ float w2s[HID * OUTD];
    for (int i = threadIdx.x; i < HID * OUTD; i += 256) w2s[i] = W2[i];
    __syncthreads();
    int lane = threadIdx.x & 63;
    int bat = (blockIdx.x * 256 + threadIdx.x) >> 6;
    int nbatch = (n + 7) / 8;
    if (bat < nbatch)
        agg_batch(h2q, dinv, offs, ebuf, perm, b1, w2s, b2, out, n, bat, lane);
}

// ----------------------------------------------------------------
extern "C" void kernel_launch(void* const* d_in, const int* in_sizes, int n_in,
                              void* d_out, int out_size, void* d_ws, size_t ws_size,
                              hipStream_t stream) {
    const float* x  = (const float*)d_in[0];
    const int*   ei = (const int*)d_in[1];
    const float* b1 = (const float*)d_in[3];
    const float* W1 = (const float*)d_in[2];
    const float* W2 = (const float*)d_in[4];
    const float* b2 = (const float*)d_in[5];
    float* out = (float*)d_out;

    int n = in_sizes[0] / IN_DIM;     // 100000
    int E = in_sizes[1] / 2;          // 1000000
    int nbuk = (n + 511) >> BSH;      // 196
    int CH = (E + 255) / 256;         // 3907 (<= 4096 = 16 regs/thread)
    int ntile = (n + 15) >> 4;        // 6250

    char* ws = (char*)d_ws;
    size_t off = 0;
    auto alloc = [&](size_t bytes) { size_t p = off; off = (off + bytes + 511) & ~(size_t)511; return p; };
    __hip_bfloat16* h2    = (__hip_bfloat16*)(ws + alloc((size_t)n * HID * 2));
    signed char*    h2q   = (signed char*)(ws + alloc((size_t)(n + 16) * HID));
    float*          dinv  = (float*)(ws + alloc((size_t)n * 4));
    int*            offs  = (int*)(ws + alloc((size_t)(n + 1) * 4));
    int*            ebuf  = (int*)(ws + alloc((size_t)E * 4));
    unsigned*       sdbuf = (unsigned*)(ws + alloc((size_t)E * 4));
    int*            gh    = (int*)(ws + alloc((size_t)256 * 256 * 4));
    int*            total = (int*)(ws + alloc((size_t)256 * 4));
    int*            perm  = (int*)(ws + alloc((size_t)n * 4));

    // gemm slice cumulative splits, weighted by phase durations
    int c1 = (int)((long long)ntile * 20 / 100);
    int c2 = (int)((long long)ntile * 30 / 100);
    int c3 = (int)((long long)ntile * 65 / 100);

    int G = 1024;   // 4 blocks/CU x 256 CUs (guaranteed by __launch_bounds__(256,4))
    void* args[] = {
        (void*)&ei, (void*)&E, (void*)&CH, (void*)&nbuk, (void*)&n,
        (void*)&x, (void*)&W1, (void*)&h2, (void*)&h2q, (void*)&dinv,
        (void*)&offs, (void*)&ebuf, (void*)&sdbuf, (void*)&gh, (void*)&total, (void*)&perm,
        (void*)&b1, (void*)&W2, (void*)&b2, (void*)&out,
        (void*)&G, (void*)&c1, (void*)&c2, (void*)&c3, (void*)&ntile
    };
    hipError_t err = hipLaunchCooperativeKernel((void*)k_mega, dim3(G), dim3(256),
                                                args, 0, stream);
    if (err == hipSuccess) return;
    (void)hipGetLastError();   // clear sticky error, use fallback

    // -------- fallback: proven 6-launch path (R17) --------
    const int GB = 256;
    int nbatch = (n + 7) / 8;
    int ablk = (nbatch + 3) / 4;
    int qblk = (ntile + 1 + 3) / 4;

    k_hist   <<<256 + GB,  256, 0, stream>>>(ei + E, gh, E, CH,
                                             x, W1, h2, n, 0, c1, GB);
    k_colscan<<<nbuk + GB, 256, 0, stream>>>(gh, total, nbuk,
                                             x, W1, h2, n, c1, c2, GB);
    k_scat   <<<256 + GB,  256, 0, stream>>>(ei, gh, total, sdbuf, E, CH, nbuk,
                                             x, W1, h2, n, c2, c3, GB);
    k_csr    <<<nbuk + GB, 256, 0, stream>>>(sdbuf, total, offs, dinv, ebuf, perm, n, nbuk,
                                             x, W1, h2, c3, ntile, GB);
    k_quant  <<<qblk, 256, 0, stream>>>(h2, dinv, h2q, n);
    k_agg    <<<ablk, 256, 0, stream>>>(h2q, dinv, offs, ebuf, perm, b1, W2, b2, out, n);
}

// Round 19
// 80.860 us; speedup vs baseline: 9.2934x; 9.2934x over previous
//
#include <hip/hip_runtime.h>
#include <hip/hip_bf16.h>
#include <math.h>

constexpr int IN_DIM = 128;
constexpr int HID    = 64;
constexpr int OUTD   = 16;
constexpr int BSH    = 9;       // bucket shift: bucket = dst >> 9 (512 nodes/bucket)
constexpr float QS   = 4.0f;    // fixed quant range: |h*dinv| < 4 analytically

typedef __attribute__((ext_vector_type(8))) short short8v;
typedef __attribute__((ext_vector_type(4))) float f32x4;

// NOTE: harness delivers integer inputs as int32.
// NOTE: no global atomics — LDS-privatized partition (R9/R10: 1M device atomics
//       cost ~32B HBM write-through each).
// NOTE: int8 h2q + sdot4 byte-select agg; zero row at index n for invalid slots.
//       agg is random-line-request-rate bound at 1 request/edge (~25us floor).
// NOTE: gemm spread over the 4 front launches (hides its ~12us under the
//       latency-bound partition chain).
// NOTE: R18 MEASURED: cooperative grid.sync() mega-kernel = 751us (9x WORSE) —
//       gfx950 grid-wide sync spin-polls through L2/HBM (200MB FETCH of spin
//       traffic). Multi-launch with ~1-2us gaps is the right structure here.

#if __has_builtin(__builtin_amdgcn_sdot4)
#define SDOT4(a, b, c) __builtin_amdgcn_sdot4((int)(a), (int)(b), (c), false)
#else
__device__ __forceinline__ int SDOT4(unsigned a, unsigned b, int c) {
    return c + (int)(signed char)(a) * (int)(signed char)(b)
             + (int)(signed char)(a >> 8)  * (int)(signed char)(b >> 8)
             + (int)(signed char)(a >> 16) * (int)(signed char)(b >> 16)
             + (int)(signed char)(a >> 24) * (int)(signed char)(b >> 24);
}
#endif

// ---------------------------------------------------------------- block-wide exclusive scan of 256 ints
__device__ __forceinline__ int blockScan256(int v, volatile int* wsum) {
    int tid = threadIdx.x, lane = tid & 63, w = tid >> 6;
    int x = v;
#pragma unroll
    for (int off = 1; off < 64; off <<= 1) {
        int t = __shfl_up(x, off, 64);
        if (lane >= off) x += t;
    }
    if (lane == 63) wsum[w] = x;
    __syncthreads();
    int add = 0;
#pragma unroll
    for (int ww = 0; ww < 4; ++ww) if (ww < w) add += wsum[ww];
    int ex = x + add - v;
    __syncthreads();
    return ex;
}

// ---------------------------------------------------------------- MFMA gemm slice: h2[t0..t1) = x @ W1 (bf16, unscaled)
__device__ __forceinline__ void gemm_slice(const float* __restrict__ x,
                                           const float* __restrict__ W1,
                                           __hip_bfloat16* __restrict__ h2,
                                           int n, int t0, int t1,
                                           int gwid, int gnw) {
    int lane = threadIdx.x & 63;
    int m16  = lane & 15;
    int kg   = lane >> 4;
    if (t0 >= t1) return;

    union { __hip_bfloat16 b; unsigned short u; } cv;

    short8v bfr[4][4];
#pragma unroll
    for (int s = 0; s < 4; ++s)
#pragma unroll
        for (int t = 0; t < 4; ++t) {
            const float* wp = W1 + (size_t)(32 * s + 8 * kg) * HID + 16 * t + m16;
#pragma unroll
            for (int e = 0; e < 8; ++e) {
                cv.b = __float2bfloat16(wp[(size_t)e * HID]);
                bfr[s][t][e] = (short)cv.u;
            }
        }

    for (int tile = t0 + gwid; tile < t1; tile += gnw) {
        int base = tile * 16;
        int row = base + m16; if (row > n - 1) row = n - 1;
        const float* xrow = x + (size_t)row * IN_DIM + 8 * kg;

        short8v a[4];
#pragma unroll
        for (int s = 0; s < 4; ++s) {
            float4 lo = *(const float4*)(xrow + 32 * s);
            float4 hi = *(const float4*)(xrow + 32 * s + 4);
            cv.b = __float2bfloat16(lo.x); a[s][0] = (short)cv.u;
            cv.b = __float2bfloat16(lo.y); a[s][1] = (short)cv.u;
            cv.b = __float2bfloat16(lo.z); a[s][2] = (short)cv.u;
            cv.b = __float2bfloat16(lo.w); a[s][3] = (short)cv.u;
            cv.b = __float2bfloat16(hi.x); a[s][4] = (short)cv.u;
            cv.b = __float2bfloat16(hi.y); a[s][5] = (short)cv.u;
            cv.b = __float2bfloat16(hi.z); a[s][6] = (short)cv.u;
            cv.b = __float2bfloat16(hi.w); a[s][7] = (short)cv.u;
        }

        f32x4 acc[4];
#pragma unroll
        for (int t = 0; t < 4; ++t) acc[t] = (f32x4){0.f, 0.f, 0.f, 0.f};
#pragma unroll
        for (int s = 0; s < 4; ++s) {
#pragma unroll
            for (int t = 0; t < 4; ++t)
                acc[t] = __builtin_amdgcn_mfma_f32_16x16x32_bf16(a[s], bfr[s][t], acc[t], 0, 0, 0);
        }

#pragma unroll
        for (int r = 0; r < 4; ++r) {
            int node = base + 4 * kg + r;
            if (node < n) {
                __hip_bfloat16* hp = h2 + (size_t)node * HID + m16;
                hp[0]  = __float2bfloat16(acc[0][r]);
                hp[16] = __float2bfloat16(acc[1][r]);
                hp[32] = __float2bfloat16(acc[2][r]);
                hp[48] = __float2bfloat16(acc[3][r]);
            }
        }
    }
}

// ---------------------------------------------------------------- pass A: bucket histogram (blocks<256) || gemm slice
__global__ __launch_bounds__(256) void k_hist(const int* __restrict__ dst,
                                              int* __restrict__ gh, int E, int CH,
                                              const float* __restrict__ x,
                                              const float* __restrict__ W1,
                                              __hip_bfloat16* __restrict__ h2,
                                              int n, int t0, int t1, int gblk) {
    if ((int)blockIdx.x >= 256) {
        int gwid = ((blockIdx.x - 256) * 256 + threadIdx.x) >> 6;
        gemm_slice(x, W1, h2, n, t0, t1, gwid, gblk * 4);
        return;
    }
    __shared__ int hist[256];
    int t = threadIdx.x, b = blockIdx.x;
    hist[t] = 0;
    __syncthreads();
    int e0 = b * CH, e1 = min(E, e0 + CH);
    for (int e = e0 + t; e < e1; e += 256)
        atomicAdd(&hist[dst[e] >> BSH], 1);          // LDS atomic
    __syncthreads();
    gh[t * 256 + b] = hist[t];                       // layout [bucket][block]
}

// ---------------------------------------------------------------- pass B: per-bucket scan (blocks<nbuk) || gemm slice
__global__ __launch_bounds__(256) void k_colscan(int* __restrict__ gh,
                                                 int* __restrict__ total, int nbuk,
                                                 const float* __restrict__ x,
                                                 const float* __restrict__ W1,
                                                 __hip_bfloat16* __restrict__ h2,
                                                 int n, int t0, int t1, int gblk) {
    if ((int)blockIdx.x >= nbuk) {
        int gwid = ((blockIdx.x - nbuk) * 256 + threadIdx.x) >> 6;
        gemm_slice(x, W1, h2, n, t0, t1, gwid, gblk * 4);
        return;
    }
    __shared__ int wsum[4];
    int bu = blockIdx.x, t = threadIdx.x;
    int v = gh[bu * 256 + t];                        // coalesced
    int ex = blockScan256(v, wsum);
    gh[bu * 256 + t] = ex;
    if (t == 255) total[bu] = ex + v;
}

// ---------------------------------------------------------------- pass C: scatter (blocks<256) || gemm slice
__global__ __launch_bounds__(256) void k_scat(const int* __restrict__ ei,
                                              const int* __restrict__ gh,
                                              const int* __restrict__ total,
                                              unsigned* __restrict__ sdbuf,
                                              int E, int CH, int nbuk,
                                              const float* __restrict__ x,
                                              const float* __restrict__ W1,
                                              __hip_bfloat16* __restrict__ h2,
                                              int n, int t0, int t1, int gblk) {
    if ((int)blockIdx.x >= 256) {
        int gwid = ((blockIdx.x - 256) * 256 + threadIdx.x) >> 6;
        gemm_slice(x, W1, h2, n, t0, t1, gwid, gblk * 4);
        return;
    }
    __shared__ int cursor[256];
    __shared__ int wsum[4];
    int t = threadIdx.x, b = blockIdx.x;
    int tv = (t < nbuk) ? total[t] : 0;
    int bbase = blockScan256(tv, wsum);              // global bucket start
    cursor[t] = gh[t * 256 + b] + bbase;             // this block's region within bucket t
    __syncthreads();
    int e0 = b * CH, e1 = min(E, e0 + CH);
    for (int e = e0 + t; e < e1; e += 256) {
        int s = ei[e];
        int d = ei[E + e];
        int pos = atomicAdd(&cursor[d >> BSH], 1);   // LDS atomic
        sdbuf[pos] = ((unsigned)s << BSH) | ((unsigned)d & 511u);
    }
}

// ---------------------------------------------------------------- pass D: CSR build + perm(desc) (blocks<nbuk) || gemm slice
__global__ __launch_bounds__(256) void k_csr(const unsigned* __restrict__ sdbuf,
                                             const int* __restrict__ total,
                                             int* __restrict__ offs,
                                             float* __restrict__ dinv,
                                             int* __restrict__ ebuf,
                                             int* __restrict__ perm,
                                             int n, int nbuk,
                                             const float* __restrict__ x,
                                             const float* __restrict__ W1,
                                             __hip_bfloat16* __restrict__ h2,
                                             int t0, int t1, int gblk) {
    if ((int)blockIdx.x >= nbuk) {
        int gwid = ((blockIdx.x - nbuk) * 256 + threadIdx.x) >> 6;
        gemm_slice(x, W1, h2, n, t0, t1, gwid, gblk * 4);
        return;
    }
    __shared__ int degl[512];
    __shared__ int offl[512];
    __shared__ int wsum[4];
    __shared__ int lohi[2];
    __shared__ int dh[128];       // degree-bin hist/cursor for perm sort
    int bu = blockIdx.x, t = threadIdx.x;
    degl[t] = 0; degl[t + 256] = 0;
    if (t < 128) dh[t] = 0;

    int tv = (t < nbuk) ? total[t] : 0;
    int ex = blockScan256(tv, wsum);
    if (t == bu) { lohi[0] = ex; lohi[1] = ex + tv; }
    __syncthreads();
    int lo = lohi[0], hi = lohi[1];

    // histogram local degrees
    for (int i = lo + t; i < hi; i += 256)
        atomicAdd(&degl[(int)(sdbuf[i] & 511u)], 1);  // LDS atomic
    __syncthreads();

    // exclusive scan of 512 degrees (2 elements per thread)
    int d0 = degl[2 * t], d1 = degl[2 * t + 1];
    int pex = blockScan256(d0 + d1, wsum);
    offl[2 * t]     = pex;
    offl[2 * t + 1] = pex + d0;
    __syncthreads();

    // write offs (absolute), dinv; build DESCENDING degree-bin histogram
    int base = bu << BSH;
    int bsize = min(512, n - base);    // nodes in this bucket
#pragma unroll
    for (int k = 0; k < 512; k += 256) {
        int i = t + k;
        int node = base + i;
        if (node <= n) offs[node] = lo + offl[i];
        if (i < bsize) {
            dinv[node] = rsqrtf((float)(degl[i] + 1));   // +1 = self loop
            atomicAdd(&dh[127 - min(degl[i], 127)], 1);  // LDS atomic (descending)
        }
    }
    __syncthreads();

    // exclusive scan of 128 degree bins
    int hv = (t < 128) ? dh[t] : 0;
    int hex = blockScan256(hv, wsum);
    if (t < 128) dh[t] = hex;          // dh becomes cursor
    __syncthreads();

    // scatter node ids into perm (degree-descending within bucket; dense)
#pragma unroll
    for (int k = 0; k < 512; k += 256) {
        int i = t + k;
        if (i < bsize) {
            int r = atomicAdd(&dh[127 - min(degl[i], 127)], 1);   // LDS atomic
            perm[base + r] = base + i;
        }
    }

    // scatter src into CSR order (bump offl as cursor)
    for (int i = lo + t; i < hi; i += 256) {
        unsigned v = sdbuf[i];
        int pos = lo + atomicAdd(&offl[(int)(v & 511u)], 1);        // LDS atomic
        ebuf[pos] = (int)(v >> BSH);
    }
}

// ---------------------------------------------------------------- pass E: WIDE quantize (fixed scale), one wave per 16-node tile
__global__ __launch_bounds__(256) void k_quant(const __hip_bfloat16* __restrict__ h2,
                                               const float* __restrict__ dinv,
                                               signed char* __restrict__ h2q, int n) {
    int lane = threadIdx.x & 63;
    int wv   = (blockIdx.x * 256 + threadIdx.x) >> 6;
    int ntile = (n + 15) >> 4;
    if (wv > ntile) return;            // tiles 0..ntile (last = zero-pad tile)
    int base = wv * 16;
    int row  = lane >> 2;        // 0..15
    int part = lane & 3;         // 16B chunk of the 64B int8 row
    int node = base + row;

    if (node >= n) {             // zero row (covers pad rows n..n+15)
        if (node < n + 16)
            ((uint4*)(h2q + (size_t)node * HID))[part] = make_uint4(0u, 0u, 0u, 0u);
        return;
    }

    const uint4* hrow = (const uint4*)(h2 + (size_t)node * HID);
    uint4 hA = hrow[2 * part];
    uint4 hB = hrow[2 * part + 1];
    float dv = dinv[node] * (127.f / QS);

#define UB(u) __uint_as_float((u) << 16)
#define UT(u) __uint_as_float((u) & 0xffff0000u)
#define QC(u) __float2int_rn(fmaxf(fminf((u), 127.f), -127.f))
    int q0 = QC(UB(hA.x) * dv), q1 = QC(UT(hA.x) * dv);
    int q2 = QC(UB(hA.y) * dv), q3 = QC(UT(hA.y) * dv);
    int q4 = QC(UB(hA.z) * dv), q5 = QC(UT(hA.z) * dv);
    int q6 = QC(UB(hA.w) * dv), q7 = QC(UT(hA.w) * dv);
    int q8 = QC(UB(hB.x) * dv), q9 = QC(UT(hB.x) * dv);
    int q10 = QC(UB(hB.y) * dv), q11 = QC(UT(hB.y) * dv);
    int q12 = QC(UB(hB.z) * dv), q13 = QC(UT(hB.z) * dv);
    int q14 = QC(UB(hB.w) * dv), q15 = QC(UT(hB.w) * dv);
#undef UB
#undef UT
#undef QC
    unsigned w0 = (q0 & 255) | ((q1 & 255) << 8) | ((q2 & 255) << 16) | ((unsigned)(q3 & 255) << 24);
    unsigned w1 = (q4 & 255) | ((q5 & 255) << 8) | ((q6 & 255) << 16) | ((unsigned)(q7 & 255) << 24);
    unsigned w2 = (q8 & 255) | ((q9 & 255) << 8) | ((q10 & 255) << 16) | ((unsigned)(q11 & 255) << 24);
    unsigned w3 = (q12 & 255) | ((q13 & 255) << 8) | ((q14 & 255) << 16) | ((unsigned)(q15 & 255) << 24);
    ((uint4*)(h2q + (size_t)node * HID))[part] = make_uint4(w0, w1, w2, w3);
}

// ---------------------------------------------------------------- fused aggregate + layer2 + log_softmax
__global__ __launch_bounds__(256) void k_agg(const signed char* __restrict__ h2q,
                                             const float* __restrict__ dinv,
                                             const int* __restrict__ offs,
                                             const int* __restrict__ ebuf,
                                             const int* __restrict__ perm,
                                             const float* __restrict__ b1,
                                             const float* __restrict__ W2,
                                             const float* __restrict__ b2,
                                             float* __restrict__ out, int n) {
    __shared__ float w2s[HID * OUTD];   // 4 KiB
    for (int i = threadIdx.x; i < HID * OUTD; i += 256) w2s[i] = W2[i];
    __syncthreads();

    const unsigned B0 = 0x00000001u, B1 = 0x00000100u, B2 = 0x00010000u, B3 = 0x01000000u;

    int lane = threadIdx.x & 63;
    int sub  = lane >> 3;
    int f    = lane & 7;
    int wid  = (blockIdx.x * 256 + threadIdx.x) >> 6;
    int idx  = wid * 8 + sub;
    bool nv  = idx < n;
    int node = nv ? perm[idx] : 0;

    float dn = dinv[node];
    float4 b1A = ((const float4*)b1)[2 * f];
    float4 b1B = ((const float4*)b1)[2 * f + 1];
    float b2l0 = b2[2 * f], b2l1 = b2[2 * f + 1];

    const uint2* q = (const uint2*)h2q;     // row = node*8 uint2s

    // self-loop term (int accumulate)
    uint2 svv = q[(size_t)node * 8 + f];
    int ai0 = SDOT4(svv.x, B0, 0), ai1 = SDOT4(svv.x, B1, 0);
    int ai2 = SDOT4(svv.x, B2, 0), ai3 = SDOT4(svv.x, B3, 0);
    int ai4 = SDOT4(svv.y, B0, 0), ai5 = SDOT4(svv.y, B1, 0);
    int ai6 = SDOT4(svv.y, B2, 0), ai7 = SDOT4(svv.y, B3, 0);

    int start = 0, end = 0;
    if (nv) {
        start = offs[node];
        end   = offs[node + 1];     // offs[n] = E sentinel
    }

    // index prefetch pipeline; invalid -> zero row at index n
    int cur = start;
    int p0 = (cur     < end) ? ebuf[cur]     : n;
    int p1 = (cur + 1 < end) ? ebuf[cur + 1] : n;
    int p2 = (cur + 2 < end) ? ebuf[cur + 2] : n;
    int p3 = (cur + 3 < end) ? ebuf[cur + 3] : n;

    while (__any(cur < end)) {
        int s0 = p0, s1 = p1, s2 = p2, s3 = p3;
        int ncur = cur + 4;

        // current gathers — issue FIRST
        uint2 g0 = q[(size_t)s0 * 8 + f];
        uint2 g1 = q[(size_t)s1 * 8 + f];
        uint2 g2 = q[(size_t)s2 * 8 + f];
        uint2 g3 = q[(size_t)s3 * 8 + f];

        // prefetch next indices — stay in flight across the dot wait
        p0 = (ncur     < end) ? ebuf[ncur]     : n;
        p1 = (ncur + 1 < end) ? ebuf[ncur + 1] : n;
        p2 = (ncur + 2 < end) ? ebuf[ncur + 2] : n;
        p3 = (ncur + 3 < end) ? ebuf[ncur + 3] : n;

#define ACCQ(g) \
        ai0 = SDOT4(g.x, B0, ai0); ai1 = SDOT4(g.x, B1, ai1); \
        ai2 = SDOT4(g.x, B2, ai2); ai3 = SDOT4(g.x, B3, ai3); \
        ai4 = SDOT4(g.y, B0, ai4); ai5 = SDOT4(g.y, B1, ai5); \
        ai6 = SDOT4(g.y, B2, ai6); ai7 = SDOT4(g.y, B3, ai7);
        ACCQ(g0) ACCQ(g1) ACCQ(g2) ACCQ(g3)
#undef ACCQ
        cur = ncur;
    }

    // dequant + scale + bias + relu : r_j = relu(ai_j * (dn*QS/127) + b1_j)
    float sc = dn * (QS / 127.f);
    float r0 = fmaxf(fmaf((float)ai0, sc, b1A.x), 0.f);
    float r1 = fmaxf(fmaf((float)ai1, sc, b1A.y), 0.f);
    float r2 = fmaxf(fmaf((float)ai2, sc, b1A.z), 0.f);
    float r3 = fmaxf(fmaf((float)ai3, sc, b1A.w), 0.f);
    float r4 = fmaxf(fmaf((float)ai4, sc, b1B.x), 0.f);
    float r5 = fmaxf(fmaf((float)ai5, sc, b1B.y), 0.f);
    float r6 = fmaxf(fmaf((float)ai6, sc, b1B.z), 0.f);
    float r7 = fmaxf(fmaf((float)ai7, sc, b1B.w), 0.f);

    float q0 = b2l0, q1 = b2l1;
    int subbase = lane & 56;
#pragma unroll
    for (int j2 = 0; j2 < 8; ++j2) {
        int srcl = subbase | j2;
        float rv0 = __shfl(r0, srcl, 64);
        float rv1 = __shfl(r1, srcl, 64);
        float rv2 = __shfl(r2, srcl, 64);
        float rv3 = __shfl(r3, srcl, 64);
        float rv4 = __shfl(r4, srcl, 64);
        float rv5 = __shfl(r5, srcl, 64);
        float rv6 = __shfl(r6, srcl, 64);
        float rv7 = __shfl(r7, srcl, 64);
        const float2* wrow = (const float2*)(w2s + 8 * j2 * OUTD + 2 * f);
        float2 w0 = wrow[0];  q0 = fmaf(rv0, w0.x, q0); q1 = fmaf(rv0, w0.y, q1);
        float2 w1 = wrow[8];  q0 = fmaf(rv1, w1.x, q0); q1 = fmaf(rv1, w1.y, q1);
        float2 w2 = wrow[16]; q0 = fmaf(rv2, w2.x, q0); q1 = fmaf(rv2, w2.y, q1);
        float2 w3 = wrow[24]; q0 = fmaf(rv3, w3.x, q0); q1 = fmaf(rv3, w3.y, q1);
        float2 w4 = wrow[32]; q0 = fmaf(rv4, w4.x, q0); q1 = fmaf(rv4, w4.y, q1);
        float2 w5 = wrow[40]; q0 = fmaf(rv5, w5.x, q0); q1 = fmaf(rv5, w5.y, q1);
        float2 w6 = wrow[48]; q0 = fmaf(rv6, w6.x, q0); q1 = fmaf(rv6, w6.y, q1);
        float2 w7 = wrow[56]; q0 = fmaf(rv7, w7.x, q0); q1 = fmaf(rv7, w7.y, q1);
    }

    float m = fmaxf(q0, q1);
    m = fmaxf(m, __shfl_xor(m, 1, 64));
    m = fmaxf(m, __shfl_xor(m, 2, 64));
    m = fmaxf(m, __shfl_xor(m, 4, 64));
    float ssum = __expf(q0 - m) + __expf(q1 - m);
    ssum += __shfl_xor(ssum, 1, 64);
    ssum += __shfl_xor(ssum, 2, 64);
    ssum += __shfl_xor(ssum, 4, 64);
    float lg = __logf(ssum);

    if (nv) {
        float2 o = make_float2(q0 - m - lg, q1 - m - lg);
        *(float2*)(out + (size_t)node * OUTD + 2 * f) = o;
    }
}

// ----------------------------------------------------------------
extern "C" void kernel_launch(void* const* d_in, const int* in_sizes, int n_in,
                              void* d_out, int out_size, void* d_ws, size_t ws_size,
                              hipStream_t stream) {
    const float* x  = (const float*)d_in[0];
    const int*   ei = (const int*)d_in[1];      // int32 (harness converts int64)
    const float* W1 = (const float*)d_in[2];
    const float* b1 = (const float*)d_in[3];
    const float* W2 = (const float*)d_in[4];
    const float* b2 = (const float*)d_in[5];
    float* out = (float*)d_out;

    int n = in_sizes[0] / IN_DIM;     // 100000
    int E = in_sizes[1] / 2;          // 1000000
    int nbuk = (n + 511) >> BSH;      // 196 (must be <= 256)
    int CH = (E + 255) / 256;         // edges per partition block
    int ntile = (n + 15) >> 4;        // 6250

    char* ws = (char*)d_ws;
    size_t off = 0;
    auto alloc = [&](size_t bytes) { size_t p = off; off = (off + bytes + 511) & ~(size_t)511; return p; };
    __hip_bfloat16* h2    = (__hip_bfloat16*)(ws + alloc((size_t)n * HID * 2));   // 12.8 MB
    signed char*    h2q   = (signed char*)(ws + alloc((size_t)(n + 16) * HID));   // 6.4 MB (+zero pad rows)
    float*          dinv  = (float*)(ws + alloc((size_t)n * 4));
    int*            offs  = (int*)(ws + alloc((size_t)(n + 1) * 4));
    int*            ebuf  = (int*)(ws + alloc((size_t)E * 4));                    // 4 MB
    unsigned*       sdbuf = (unsigned*)(ws + alloc((size_t)E * 4));               // 4 MB (packed)
    int*            gh    = (int*)(ws + alloc((size_t)256 * 256 * 4));            // 256 KB
    int*            total = (int*)(ws + alloc((size_t)256 * 4));
    int*            perm  = (int*)(ws + alloc((size_t)n * 4));                    // 0.4 MB

    const int GB = 256;               // gemm blocks per front launch
    int c1 = (int)((long long)ntile * 35 / 100);
    int c2 = (int)((long long)ntile * 50 / 100);
    int c3 = (int)((long long)ntile * 80 / 100);

    int nbatch = (n + 7) / 8;
    int ablk = (nbatch + 3) / 4;
    int qblk = (ntile + 1 + 3) / 4;   // +1 = zero-pad tile

    k_hist   <<<256 + GB,  256, 0, stream>>>(ei + E, gh, E, CH,
                                             x, W1, h2, n, 0, c1, GB);
    k_colscan<<<nbuk + GB, 256, 0, stream>>>(gh, total, nbuk,
                                             x, W1, h2, n, c1, c2, GB);
    k_scat   <<<256 + GB,  256, 0, stream>>>(ei, gh, total, sdbuf, E, CH, nbuk,
                                             x, W1, h2, n, c2, c3, GB);
    k_csr    <<<nbuk + GB, 256, 0, stream>>>(sdbuf, total, offs, dinv, ebuf, perm, n, nbuk,
                                             x, W1, h2, c3, ntile, GB);
    k_quant  <<<qblk, 256, 0, stream>>>(h2, dinv, h2q, n);
    k_agg    <<<ablk, 256, 0, stream>>>(h2q, dinv, offs, ebuf, perm, b1, W2, b2, out, n);
}